// Round 2
// baseline (7432.268 us; speedup 1.0000x reference)
//
#include <hip/hip_runtime.h>
#include <hip/hip_fp16.h>

typedef unsigned int u32;

#define TT 2048
#define HD 256
#define G4 1024
#define NT 16
#define START_TAG 14
#define STOP_TAG 15
#define NEGV (-10000.0f)

typedef _Float16 half2v __attribute__((ext_vector_type(2)));

__device__ __forceinline__ float fdot2u(u32 a, u32 b, float c) {
    return __builtin_amdgcn_fdot2(__builtin_bit_cast(half2v, a),
                                  __builtin_bit_cast(half2v, b), c, false);
}
__device__ __forceinline__ float sigmf_(float x) { return 1.0f / (1.0f + __expf(-x)); }
__device__ __forceinline__ float tanhf_(float x) {
    float e = __expf(-2.0f * fabsf(x));
    return copysignf((1.0f - e) / (1.0f + e), x);
}

// K0: pack w_hh to f16 pairs. Register part [dir][1024][96], LDS part transposed [dir][32][1024].
__global__ __launch_bounds__(128) void pack_whh(const float* whh_f, const float* whh_b,
                                                u32* wregp, u32* wldsp) {
    int row = blockIdx.x, dir = blockIdx.y, k = threadIdx.x;
    const float* w = (dir ? whh_b : whh_f) + (size_t)row * HD;
    if (k < 96) {
        u32 lo = __half_as_ushort(__float2half(w[2 * k]));
        u32 hi = __half_as_ushort(__float2half(w[2 * k + 1]));
        wregp[((size_t)dir * G4 + row) * 96 + k] = lo | (hi << 16);
    } else {
        int q = k - 96;
        u32 lo = __half_as_ushort(__float2half(w[192 + 2 * q]));
        u32 hi = __half_as_ushort(__float2half(w[193 + 2 * q]));
        wldsp[((size_t)dir * 32 + q) * G4 + row] = lo | (hi << 16);
    }
}

// K1: G[dir][t][r] = dot(embed[sent[t or T-1-t]], w_ih[r]) + b[r]   (f32 exact)
__global__ __launch_bounds__(256) void input_gemm(const int* sent, const float* embed,
                                                  const float* wih_f, const float* b_f,
                                                  const float* wih_b, const float* b_b,
                                                  float* G) {
    __shared__ float X[32][HD];   // 32KB
    __shared__ int rows[32];
    int tid = threadIdx.x;
    int dir = blockIdx.z;
    int t0 = blockIdx.x * 32;
    if (tid < 32) {
        int tg = t0 + tid;
        rows[tid] = sent[dir ? (TT - 1 - tg) : tg];
    }
    __syncthreads();
    for (int i = 0; i < 32; i++) X[i][tid] = embed[(size_t)rows[i] * HD + tid];
    __syncthreads();
    int r = blockIdx.y * 256 + tid;
    const float* wrow = (dir ? wih_b : wih_f) + (size_t)r * HD;
    float acc[32];
#pragma unroll
    for (int i = 0; i < 32; i++) acc[i] = 0.0f;
    for (int kc = 0; kc < HD / 4; kc++) {
        float4 w4 = ((const float4*)wrow)[kc];
#pragma unroll
        for (int i = 0; i < 32; i++) {
            float4 x4 = *((const float4*)&X[i][kc * 4]);
            acc[i] += w4.x * x4.x + w4.y * x4.y + w4.z * x4.z + w4.w * x4.w;
        }
    }
    float bias = (dir ? b_b : b_f)[r];
    for (int i = 0; i < 32; i++)
        G[((size_t)dir * TT + t0 + i) * G4 + r] = acc[i] + bias;
}

// K2: persistent per-direction LSTM recurrence. 512 threads, 2 gate rows each
// (rows tid and tid+512): thread j<256 gets (i_j, g_j), thread j+256 gets (f_j, o_j).
// W_hh f16: 2x96 u32 in VGPRs (K=0..191) + [32][1024] u32 in LDS (K=192..255).
// __launch_bounds__(512,2): 2 waves/SIMD -> 256 VGPR cap -> no spill.
__global__ __launch_bounds__(512, 2) void lstm_rec(const u32* wregp, const u32* wldsp,
                                                   const float* G, const float* h0,
                                                   const float* c0, float* H) {
    __shared__ u32 Wl[32 * G4];            // 128KB
    __shared__ float fo[2][256];           // sig(f), sig(o) exchange
    __shared__ __align__(16) u32 h2[128];  // 256 f16 of h
    int tid = threadIdx.x;
    int dir = blockIdx.x;
    {   // stage LDS weight slice, vectorized
        const uint4* src = (const uint4*)(wldsp + (size_t)dir * 32 * G4);
        uint4* dst = (uint4*)Wl;
        for (int i = tid; i < 32 * G4 / 4; i += 512) dst[i] = src[i];
    }
    u32 w0[96], w1[96];
    const uint4* wp0 = (const uint4*)(wregp + ((size_t)dir * G4 + tid) * 96);
    const uint4* wp1 = (const uint4*)(wregp + ((size_t)dir * G4 + tid + 512) * 96);
#pragma unroll
    for (int i = 0; i < 24; i++) {
        uint4 a = wp0[i];
        w0[4 * i] = a.x; w0[4 * i + 1] = a.y; w0[4 * i + 2] = a.z; w0[4 * i + 3] = a.w;
        uint4 b = wp1[i];
        w1[4 * i] = b.x; w1[4 * i + 1] = b.y; w1[4 * i + 2] = b.z; w1[4 * i + 3] = b.w;
    }
    float cst = 0.0f;
    if (tid < HD) {
        cst = c0[dir * HD + tid];
        ((unsigned short*)h2)[tid] = __half_as_ushort(__float2half(h0[dir * HD + tid]));
    }
    __syncthreads();
    const float* Gd = G + (size_t)dir * TT * G4;
    float* Hd = H + (size_t)dir * TT * HD;
    for (int t = 0; t < TT; t++) {
        float g0 = Gd[(size_t)t * G4 + tid];          // issued early
        float g1 = Gd[(size_t)t * G4 + tid + 512];
        float a0 = 0.0f, a1 = 0.0f;
#pragma unroll
        for (int p = 0; p < 96; p += 4) {
            uint4 h4 = *((const uint4*)&h2[p]);       // wave-uniform broadcast
            a0 = fdot2u(w0[p + 0], h4.x, a0); a1 = fdot2u(w1[p + 0], h4.x, a1);
            a0 = fdot2u(w0[p + 1], h4.y, a0); a1 = fdot2u(w1[p + 1], h4.y, a1);
            a0 = fdot2u(w0[p + 2], h4.z, a0); a1 = fdot2u(w1[p + 2], h4.z, a1);
            a0 = fdot2u(w0[p + 3], h4.w, a0); a1 = fdot2u(w1[p + 3], h4.w, a1);
        }
#pragma unroll
        for (int q = 0; q < 32; q += 4) {
            uint4 h4 = *((const uint4*)&h2[96 + q]);
            a0 = fdot2u(Wl[(q + 0) * G4 + tid], h4.x, a0);
            a1 = fdot2u(Wl[(q + 0) * G4 + tid + 512], h4.x, a1);
            a0 = fdot2u(Wl[(q + 1) * G4 + tid], h4.y, a0);
            a1 = fdot2u(Wl[(q + 1) * G4 + tid + 512], h4.y, a1);
            a0 = fdot2u(Wl[(q + 2) * G4 + tid], h4.z, a0);
            a1 = fdot2u(Wl[(q + 2) * G4 + tid + 512], h4.z, a1);
            a0 = fdot2u(Wl[(q + 3) * G4 + tid], h4.w, a0);
            a1 = fdot2u(Wl[(q + 3) * G4 + tid + 512], h4.w, a1);
        }
        a0 += g0; a1 += g1;
        if (tid >= 256) {                    // a0 = f_j, a1 = o_j  (j = tid-256)
            fo[0][tid - 256] = sigmf_(a0);
            fo[1][tid - 256] = sigmf_(a1);
        }
        __syncthreads();
        if (tid < 256) {                     // a0 = i_j, a1 = g_j  (j = tid)
            float sf = fo[0][tid], so = fo[1][tid];
            cst = sf * cst + sigmf_(a0) * tanhf_(a1);
            float h = so * tanhf_(cst);
            Hd[(size_t)t * HD + tid] = h;
            ((unsigned short*)h2)[tid] = __half_as_ushort(__float2half(h));
        }
        __syncthreads();
    }
}

// K3: feats[t][n] = hf[t]·w_out[n][0:256] + hb_scan[T-1-t]·w_out[n][256:512] + b_out[n]
__global__ __launch_bounds__(256) void feats_kernel(const float* H, const float* w_out,
                                                    const float* b_out, float* feats) {
    int idx = blockIdx.x * blockDim.x + threadIdx.x;
    int t = idx >> 4, n = idx & 15;
    const float* hf = H + (size_t)t * HD;
    const float* hb = H + ((size_t)TT + (TT - 1 - t)) * HD;
    const float* w = w_out + (size_t)n * (2 * HD);
    float a = b_out[n];
    for (int k = 0; k < HD; k += 4) {
        float4 h4 = *((const float4*)&hf[k]);
        float4 w4 = *((const float4*)&w[k]);
        a += h4.x * w4.x + h4.y * w4.y + h4.z * w4.z + h4.w * w4.w;
    }
    for (int k = 0; k < HD; k += 4) {
        float4 h4 = *((const float4*)&hb[k]);
        float4 w4 = *((const float4*)&w[HD + k]);
        a += h4.x * w4.x + h4.y * w4.y + h4.z * w4.z + h4.w * w4.w;
    }
    feats[(size_t)t * NT + n] = a;
}

// K4: Viterbi + backtrack, single wave, shuffle-only recurrence (no barriers in loop).
// lane = next*4 + prev_quad; lane l (l<16) carries fv[l] between steps.
__global__ __launch_bounds__(64) void viterbi_kernel(const float* feats, const float* trans,
                                                     float* out) {
    __shared__ float fvs[NT];
    __shared__ unsigned char bps[TT][NT];   // 32KB
    int lane = threadIdx.x;
    int n = lane >> 2, pg = lane & 3;
    float4 tr4 = *((const float4*)&trans[n * NT + pg * 4]);
    float fv = (lane == START_TAG) ? 0.0f : NEGV;
    float ftn = feats[n];                    // prefetch t=0
    for (int t = 0; t < TT; t++) {
        float f0 = __shfl(fv, pg * 4 + 0, 64);
        float f1 = __shfl(fv, pg * 4 + 1, 64);
        float f2 = __shfl(fv, pg * 4 + 2, 64);
        float f3 = __shfl(fv, pg * 4 + 3, 64);
        float ft = ftn;
        if (t + 1 < TT) ftn = feats[(t + 1) * NT + n];   // prefetch next
        float v = f0 + tr4.x; int bi = pg * 4 + 0;
        float v1 = f1 + tr4.y; if (v1 > v) { v = v1; bi = pg * 4 + 1; }
        float v2 = f2 + tr4.z; if (v2 > v) { v = v2; bi = pg * 4 + 2; }
        float v3 = f3 + tr4.w; if (v3 > v) { v = v3; bi = pg * 4 + 3; }
        // butterfly over the 4 prev-quads of this next-tag; first-index tie-break
#pragma unroll
        for (int m = 1; m <= 2; m <<= 1) {
            float ov = __shfl_xor(v, m, 64);
            int ob = __shfl_xor(bi, m, 64);
            if (ov > v || (ov == v && ob < bi)) { v = ov; bi = ob; }
        }
        if (pg == 0) bps[t][n] = (unsigned char)bi;
        fv = __shfl(v + ft, (lane & 15) * 4, 64);        // lane l<16 <- group l's result
    }
    if (lane < NT) fvs[lane] = fv;
    __syncthreads();
    if (lane == 0) {
        float best = -3.0e38f; int bt = 0;
        for (int p = 0; p < NT; p++) {
            float tv = fvs[p] + trans[STOP_TAG * NT + p];
            if (tv > best) { best = tv; bt = p; }
        }
        out[0] = best;
        int tag = bt;
        out[TT] = (float)tag;                  // path[T-1]
        for (int t = TT - 2; t >= 0; t--) {
            tag = bps[t + 1][tag];
            out[1 + t] = (float)tag;
        }
    }
}

extern "C" void kernel_launch(void* const* d_in, const int* in_sizes, int n_in,
                              void* d_out, int out_size, void* d_ws, size_t ws_size,
                              hipStream_t stream) {
    const int* sent = (const int*)d_in[0];
    const float* embed = (const float*)d_in[1];
    const float* wih_f = (const float*)d_in[2];
    const float* whh_f = (const float*)d_in[3];
    const float* b_f = (const float*)d_in[4];
    const float* wih_b = (const float*)d_in[5];
    const float* whh_b = (const float*)d_in[6];
    const float* b_b = (const float*)d_in[7];
    const float* w_out = (const float*)d_in[8];
    const float* b_out = (const float*)d_in[9];
    const float* trans = (const float*)d_in[10];
    const float* h0 = (const float*)d_in[11];
    const float* c0 = (const float*)d_in[12];
    float* out = (float*)d_out;
    char* ws = (char*)d_ws;

    float* G = (float*)(ws);                               // 2*2048*1024*4 = 16MB
    float* H = (float*)(ws + (size_t)16 * 1024 * 1024);    // 2*2048*256*4  = 4MB
    float* feats = (float*)(ws + (size_t)20 * 1024 * 1024);// 128KB
    u32* wregp = (u32*)(ws + (size_t)21 * 1024 * 1024);    // 768KB
    u32* wldsp = (u32*)(ws + (size_t)22 * 1024 * 1024);    // 256KB

    pack_whh<<<dim3(G4, 2), 128, 0, stream>>>(whh_f, whh_b, wregp, wldsp);
    input_gemm<<<dim3(TT / 32, G4 / 256, 2), 256, 0, stream>>>(sent, embed, wih_f, b_f,
                                                               wih_b, b_b, G);
    lstm_rec<<<dim3(2), 512, 0, stream>>>(wregp, wldsp, G, h0, c0, H);
    feats_kernel<<<dim3(TT * NT / 256), 256, 0, stream>>>(H, w_out, b_out, feats);
    viterbi_kernel<<<dim3(1), 64, 0, stream>>>(feats, trans, out);
}

// Round 3
// 7425.528 us; speedup vs baseline: 1.0009x; 1.0009x over previous
//
#include <hip/hip_runtime.h>
#include <hip/hip_fp16.h>

typedef unsigned int u32;

#define TT 2048
#define HD 256
#define G4 1024
#define NT 16
#define START_TAG 14
#define STOP_TAG 15
#define NEGV (-10000.0f)

typedef _Float16 half2v __attribute__((ext_vector_type(2)));

__device__ __forceinline__ float fdot2u(u32 a, u32 b, float c) {
    return __builtin_amdgcn_fdot2(__builtin_bit_cast(half2v, a),
                                  __builtin_bit_cast(half2v, b), c, false);
}
__device__ __forceinline__ float sigmf_(float x) { return 1.0f / (1.0f + __expf(-x)); }
__device__ __forceinline__ float tanhf_(float x) {
    float e = __expf(-2.0f * fabsf(x));
    return copysignf((1.0f - e) / (1.0f + e), x);
}

// K0: pack w_hh to f16 pairs. Register part [dir][1024][96], LDS part transposed [dir][32][1024].
__global__ __launch_bounds__(128) void pack_whh(const float* whh_f, const float* whh_b,
                                                u32* wregp, u32* wldsp) {
    int row = blockIdx.x, dir = blockIdx.y, k = threadIdx.x;
    const float* w = (dir ? whh_b : whh_f) + (size_t)row * HD;
    if (k < 96) {
        u32 lo = __half_as_ushort(__float2half(w[2 * k]));
        u32 hi = __half_as_ushort(__float2half(w[2 * k + 1]));
        wregp[((size_t)dir * G4 + row) * 96 + k] = lo | (hi << 16);
    } else {
        int q = k - 96;
        u32 lo = __half_as_ushort(__float2half(w[192 + 2 * q]));
        u32 hi = __half_as_ushort(__float2half(w[193 + 2 * q]));
        wldsp[((size_t)dir * 32 + q) * G4 + row] = lo | (hi << 16);
    }
}

// K1: G[dir][t][r] = dot(embed[sent[t or T-1-t]], w_ih[r]) + b[r]   (f32 exact)
__global__ __launch_bounds__(256) void input_gemm(const int* sent, const float* embed,
                                                  const float* wih_f, const float* b_f,
                                                  const float* wih_b, const float* b_b,
                                                  float* G) {
    __shared__ float X[32][HD];   // 32KB
    __shared__ int rows[32];
    int tid = threadIdx.x;
    int dir = blockIdx.z;
    int t0 = blockIdx.x * 32;
    if (tid < 32) {
        int tg = t0 + tid;
        rows[tid] = sent[dir ? (TT - 1 - tg) : tg];
    }
    __syncthreads();
    for (int i = 0; i < 32; i++) X[i][tid] = embed[(size_t)rows[i] * HD + tid];
    __syncthreads();
    int r = blockIdx.y * 256 + tid;
    const float* wrow = (dir ? wih_b : wih_f) + (size_t)r * HD;
    float acc[32];
#pragma unroll
    for (int i = 0; i < 32; i++) acc[i] = 0.0f;
    for (int kc = 0; kc < HD / 4; kc++) {
        float4 w4 = ((const float4*)wrow)[kc];
#pragma unroll
        for (int i = 0; i < 32; i++) {
            float4 x4 = *((const float4*)&X[i][kc * 4]);
            acc[i] += w4.x * x4.x + w4.y * x4.y + w4.z * x4.z + w4.w * x4.w;
        }
    }
    float bias = (dir ? b_b : b_f)[r];
    for (int i = 0; i < 32; i++)
        G[((size_t)dir * TT + t0 + i) * G4 + r] = acc[i] + bias;
}

// K2: persistent per-direction LSTM recurrence. 512 threads, 2 gate rows each
// (rows tid and tid+512): thread j<256 gets (i_j, g_j), thread j+256 gets (f_j, o_j).
// W_hh f16: 2x96 u32 in VGPRs (K=0..191) + [32][1024] u32 in LDS (K=192..255).
// amdgpu_waves_per_eu(2,2): exactly 2 waves/SIMD -> 256-VGPR budget -> no spill
// (launch_bounds minWaves arg empirically gave a 128 cap in R2; attribute is explicit).
__global__ __launch_bounds__(512)
__attribute__((amdgpu_waves_per_eu(2, 2)))
void lstm_rec(const u32* wregp, const u32* wldsp,
              const float* G, const float* h0,
              const float* c0, float* H) {
    __shared__ u32 Wl[32 * G4];            // 128KB
    __shared__ float fo[2][256];           // sig(f), sig(o) exchange
    __shared__ __align__(16) u32 h2[128];  // 256 f16 of h
    int tid = threadIdx.x;
    int dir = blockIdx.x;
    {   // stage LDS weight slice, vectorized
        const uint4* src = (const uint4*)(wldsp + (size_t)dir * 32 * G4);
        uint4* dst = (uint4*)Wl;
        for (int i = tid; i < 32 * G4 / 4; i += 512) dst[i] = src[i];
    }
    u32 w0[96], w1[96];
    const uint4* wp0 = (const uint4*)(wregp + ((size_t)dir * G4 + tid) * 96);
    const uint4* wp1 = (const uint4*)(wregp + ((size_t)dir * G4 + tid + 512) * 96);
#pragma unroll
    for (int i = 0; i < 24; i++) {
        uint4 a = wp0[i];
        w0[4 * i] = a.x; w0[4 * i + 1] = a.y; w0[4 * i + 2] = a.z; w0[4 * i + 3] = a.w;
        uint4 b = wp1[i];
        w1[4 * i] = b.x; w1[4 * i + 1] = b.y; w1[4 * i + 2] = b.z; w1[4 * i + 3] = b.w;
    }
    float cst = 0.0f;
    if (tid < HD) {
        cst = c0[dir * HD + tid];
        ((unsigned short*)h2)[tid] = __half_as_ushort(__float2half(h0[dir * HD + tid]));
    }
    __syncthreads();
    const float* Gd = G + (size_t)dir * TT * G4;
    float* Hd = H + (size_t)dir * TT * HD;
    for (int t = 0; t < TT; t++) {
        float g0 = Gd[(size_t)t * G4 + tid];          // issued early
        float g1 = Gd[(size_t)t * G4 + tid + 512];
        float a0 = 0.0f, a1 = 0.0f;
#pragma unroll
        for (int p = 0; p < 96; p += 4) {
            uint4 h4 = *((const uint4*)&h2[p]);       // wave-uniform broadcast
            a0 = fdot2u(w0[p + 0], h4.x, a0); a1 = fdot2u(w1[p + 0], h4.x, a1);
            a0 = fdot2u(w0[p + 1], h4.y, a0); a1 = fdot2u(w1[p + 1], h4.y, a1);
            a0 = fdot2u(w0[p + 2], h4.z, a0); a1 = fdot2u(w1[p + 2], h4.z, a1);
            a0 = fdot2u(w0[p + 3], h4.w, a0); a1 = fdot2u(w1[p + 3], h4.w, a1);
        }
#pragma unroll
        for (int q = 0; q < 32; q += 4) {
            uint4 h4 = *((const uint4*)&h2[96 + q]);
            a0 = fdot2u(Wl[(q + 0) * G4 + tid], h4.x, a0);
            a1 = fdot2u(Wl[(q + 0) * G4 + tid + 512], h4.x, a1);
            a0 = fdot2u(Wl[(q + 1) * G4 + tid], h4.y, a0);
            a1 = fdot2u(Wl[(q + 1) * G4 + tid + 512], h4.y, a1);
            a0 = fdot2u(Wl[(q + 2) * G4 + tid], h4.z, a0);
            a1 = fdot2u(Wl[(q + 2) * G4 + tid + 512], h4.z, a1);
            a0 = fdot2u(Wl[(q + 3) * G4 + tid], h4.w, a0);
            a1 = fdot2u(Wl[(q + 3) * G4 + tid + 512], h4.w, a1);
        }
        a0 += g0; a1 += g1;
        if (tid >= 256) {                    // a0 = f_j, a1 = o_j  (j = tid-256)
            fo[0][tid - 256] = sigmf_(a0);
            fo[1][tid - 256] = sigmf_(a1);
        }
        __syncthreads();
        if (tid < 256) {                     // a0 = i_j, a1 = g_j  (j = tid)
            float sf = fo[0][tid], so = fo[1][tid];
            cst = sf * cst + sigmf_(a0) * tanhf_(a1);
            float h = so * tanhf_(cst);
            Hd[(size_t)t * HD + tid] = h;
            ((unsigned short*)h2)[tid] = __half_as_ushort(__float2half(h));
        }
        __syncthreads();
    }
}

// K3: feats[t][n] = hf[t]·w_out[n][0:256] + hb_scan[T-1-t]·w_out[n][256:512] + b_out[n]
__global__ __launch_bounds__(256) void feats_kernel(const float* H, const float* w_out,
                                                    const float* b_out, float* feats) {
    int idx = blockIdx.x * blockDim.x + threadIdx.x;
    int t = idx >> 4, n = idx & 15;
    const float* hf = H + (size_t)t * HD;
    const float* hb = H + ((size_t)TT + (TT - 1 - t)) * HD;
    const float* w = w_out + (size_t)n * (2 * HD);
    float a = b_out[n];
    for (int k = 0; k < HD; k += 4) {
        float4 h4 = *((const float4*)&hf[k]);
        float4 w4 = *((const float4*)&w[k]);
        a += h4.x * w4.x + h4.y * w4.y + h4.z * w4.z + h4.w * w4.w;
    }
    for (int k = 0; k < HD; k += 4) {
        float4 h4 = *((const float4*)&hb[k]);
        float4 w4 = *((const float4*)&w[HD + k]);
        a += h4.x * w4.x + h4.y * w4.y + h4.z * w4.z + h4.w * w4.w;
    }
    feats[(size_t)t * NT + n] = a;
}

// K4: Viterbi + backtrack, single wave, shuffle-only recurrence (no barriers in loop).
// lane = next*4 + prev_quad; lane l (l<16) carries fv[l] between steps.
__global__ __launch_bounds__(64) void viterbi_kernel(const float* feats, const float* trans,
                                                     float* out) {
    __shared__ float fvs[NT];
    __shared__ unsigned char bps[TT][NT];   // 32KB
    int lane = threadIdx.x;
    int n = lane >> 2, pg = lane & 3;
    float4 tr4 = *((const float4*)&trans[n * NT + pg * 4]);
    float fv = (lane == START_TAG) ? 0.0f : NEGV;
    float ftn = feats[n];                    // prefetch t=0
    for (int t = 0; t < TT; t++) {
        float f0 = __shfl(fv, pg * 4 + 0, 64);
        float f1 = __shfl(fv, pg * 4 + 1, 64);
        float f2 = __shfl(fv, pg * 4 + 2, 64);
        float f3 = __shfl(fv, pg * 4 + 3, 64);
        float ft = ftn;
        if (t + 1 < TT) ftn = feats[(t + 1) * NT + n];   // prefetch next
        float v = f0 + tr4.x; int bi = pg * 4 + 0;
        float v1 = f1 + tr4.y; if (v1 > v) { v = v1; bi = pg * 4 + 1; }
        float v2 = f2 + tr4.z; if (v2 > v) { v = v2; bi = pg * 4 + 2; }
        float v3 = f3 + tr4.w; if (v3 > v) { v = v3; bi = pg * 4 + 3; }
        // butterfly over the 4 prev-quads of this next-tag; first-index tie-break
#pragma unroll
        for (int m = 1; m <= 2; m <<= 1) {
            float ov = __shfl_xor(v, m, 64);
            int ob = __shfl_xor(bi, m, 64);
            if (ov > v || (ov == v && ob < bi)) { v = ov; bi = ob; }
        }
        if (pg == 0) bps[t][n] = (unsigned char)bi;
        fv = __shfl(v + ft, (lane & 15) * 4, 64);        // lane l<16 <- group l's result
    }
    if (lane < NT) fvs[lane] = fv;
    __syncthreads();
    if (lane == 0) {
        float best = -3.0e38f; int bt = 0;
        for (int p = 0; p < NT; p++) {
            float tv = fvs[p] + trans[STOP_TAG * NT + p];
            if (tv > best) { best = tv; bt = p; }
        }
        out[0] = best;
        int tag = bt;
        out[TT] = (float)tag;                  // path[T-1]
        for (int t = TT - 2; t >= 0; t--) {
            tag = bps[t + 1][tag];
            out[1 + t] = (float)tag;
        }
    }
}

extern "C" void kernel_launch(void* const* d_in, const int* in_sizes, int n_in,
                              void* d_out, int out_size, void* d_ws, size_t ws_size,
                              hipStream_t stream) {
    const int* sent = (const int*)d_in[0];
    const float* embed = (const float*)d_in[1];
    const float* wih_f = (const float*)d_in[2];
    const float* whh_f = (const float*)d_in[3];
    const float* b_f = (const float*)d_in[4];
    const float* wih_b = (const float*)d_in[5];
    const float* whh_b = (const float*)d_in[6];
    const float* b_b = (const float*)d_in[7];
    const float* w_out = (const float*)d_in[8];
    const float* b_out = (const float*)d_in[9];
    const float* trans = (const float*)d_in[10];
    const float* h0 = (const float*)d_in[11];
    const float* c0 = (const float*)d_in[12];
    float* out = (float*)d_out;
    char* ws = (char*)d_ws;

    float* G = (float*)(ws);                               // 2*2048*1024*4 = 16MB
    float* H = (float*)(ws + (size_t)16 * 1024 * 1024);    // 2*2048*256*4  = 4MB
    float* feats = (float*)(ws + (size_t)20 * 1024 * 1024);// 128KB
    u32* wregp = (u32*)(ws + (size_t)21 * 1024 * 1024);    // 768KB
    u32* wldsp = (u32*)(ws + (size_t)22 * 1024 * 1024);    // 256KB

    pack_whh<<<dim3(G4, 2), 128, 0, stream>>>(whh_f, whh_b, wregp, wldsp);
    input_gemm<<<dim3(TT / 32, G4 / 256, 2), 256, 0, stream>>>(sent, embed, wih_f, b_f,
                                                               wih_b, b_b, G);
    lstm_rec<<<dim3(2), 512, 0, stream>>>(wregp, wldsp, G, h0, c0, H);
    feats_kernel<<<dim3(TT * NT / 256), 256, 0, stream>>>(H, w_out, b_out, feats);
    viterbi_kernel<<<dim3(1), 64, 0, stream>>>(feats, trans, out);
}

// Round 4
// 5187.293 us; speedup vs baseline: 1.4328x; 1.4315x over previous
//
#include <hip/hip_runtime.h>
#include <hip/hip_fp16.h>

typedef unsigned int u32;
typedef u32 u32x16 __attribute__((ext_vector_type(16)));

#define TT 2048
#define HD 256
#define G4 1024
#define NT 16
#define START_TAG 14
#define STOP_TAG 15
#define NEGV (-10000.0f)

typedef _Float16 half2v __attribute__((ext_vector_type(2)));

__device__ __forceinline__ float fdot2u(u32 a, u32 b, float c) {
    return __builtin_amdgcn_fdot2(__builtin_bit_cast(half2v, a),
                                  __builtin_bit_cast(half2v, b), c, false);
}
__device__ __forceinline__ float sigmf_(float x) { return 1.0f / (1.0f + __expf(-x)); }
__device__ __forceinline__ float tanhf_(float x) {
    float e = __expf(-2.0f * fabsf(x));
    return copysignf((1.0f - e) / (1.0f + e), x);
}

// K0: pack w_hh to f16 pairs. Register part [dir][1024][96] (u32 pair p = K 2p,2p+1).
// LDS part (p=96..127): b64-pair layout: wldsp[dir*32K + (k2*1024 + row)*2 + half],
// k2=(p-96)>>1, half=(p-96)&1  -> consumer does ds_read_b64 per row-pair.
__global__ __launch_bounds__(128) void pack_whh(const float* whh_f, const float* whh_b,
                                                u32* wregp, u32* wldsp) {
    int row = blockIdx.x, dir = blockIdx.y, k = threadIdx.x;
    const float* w = (dir ? whh_b : whh_f) + (size_t)row * HD;
    if (k < 96) {
        u32 lo = __half_as_ushort(__float2half(w[2 * k]));
        u32 hi = __half_as_ushort(__float2half(w[2 * k + 1]));
        wregp[((size_t)dir * G4 + row) * 96 + k] = lo | (hi << 16);
    } else {
        int q = k - 96;                        // 0..31
        int k2 = q >> 1, half = q & 1;
        u32 lo = __half_as_ushort(__float2half(w[192 + 2 * q]));
        u32 hi = __half_as_ushort(__float2half(w[193 + 2 * q]));
        wldsp[(size_t)dir * 32 * G4 + ((size_t)k2 * G4 + row) * 2 + half] = lo | (hi << 16);
    }
}

// K1: G[dir][t][r] = dot(embed[sent[t or T-1-t]], w_ih[r]) + b[r]   (f32 exact)
__global__ __launch_bounds__(256) void input_gemm(const int* sent, const float* embed,
                                                  const float* wih_f, const float* b_f,
                                                  const float* wih_b, const float* b_b,
                                                  float* G) {
    __shared__ float X[32][HD];   // 32KB
    __shared__ int rows[32];
    int tid = threadIdx.x;
    int dir = blockIdx.z;
    int t0 = blockIdx.x * 32;
    if (tid < 32) {
        int tg = t0 + tid;
        rows[tid] = sent[dir ? (TT - 1 - tg) : tg];
    }
    __syncthreads();
    for (int i = 0; i < 32; i++) X[i][tid] = embed[(size_t)rows[i] * HD + tid];
    __syncthreads();
    int r = blockIdx.y * 256 + tid;
    const float* wrow = (dir ? wih_b : wih_f) + (size_t)r * HD;
    float acc[32];
#pragma unroll
    for (int i = 0; i < 32; i++) acc[i] = 0.0f;
    for (int kc = 0; kc < HD / 4; kc++) {
        float4 w4 = ((const float4*)wrow)[kc];
#pragma unroll
        for (int i = 0; i < 32; i++) {
            float4 x4 = *((const float4*)&X[i][kc * 4]);
            acc[i] += w4.x * x4.x + w4.y * x4.y + w4.z * x4.z + w4.w * x4.w;
        }
    }
    float bias = (dir ? b_b : b_f)[r];
    for (int i = 0; i < 32; i++)
        G[((size_t)dir * TT + t0 + i) * G4 + r] = acc[i] + bias;
}

// per-16-u32 dot block: W holds K pairs B..B+15, h2[B..B+15] the matching h pairs
#define DOT16(W, B)                                                       \
    {                                                                     \
        uint4 ha = *((const uint4*)&h2[(B)]);                             \
        acc = fdot2u(W[0], ha.x, acc);  acc = fdot2u(W[1], ha.y, acc);    \
        acc = fdot2u(W[2], ha.z, acc);  acc = fdot2u(W[3], ha.w, acc);    \
        uint4 hb = *((const uint4*)&h2[(B) + 4]);                         \
        acc = fdot2u(W[4], hb.x, acc);  acc = fdot2u(W[5], hb.y, acc);    \
        acc = fdot2u(W[6], hb.z, acc);  acc = fdot2u(W[7], hb.w, acc);    \
        uint4 hc = *((const uint4*)&h2[(B) + 8]);                         \
        acc = fdot2u(W[8], hc.x, acc);  acc = fdot2u(W[9], hc.y, acc);    \
        acc = fdot2u(W[10], hc.z, acc); acc = fdot2u(W[11], hc.w, acc);   \
        uint4 hd = *((const uint4*)&h2[(B) + 12]);                        \
        acc = fdot2u(W[12], hd.x, acc); acc = fdot2u(W[13], hd.y, acc);   \
        acc = fdot2u(W[14], hd.z, acc); acc = fdot2u(W[15], hd.w, acc);   \
    }

// K2: persistent per-direction LSTM recurrence. 1024 threads = 1024 gate rows.
// Weights K=0..191 in SIX NAMED ext_vector SSA values (96 VGPRs, no arrays ->
// no SROA failure -> no scratch). K=192..255 in LDS, b64-paired, 2-way-free reads.
__global__ __launch_bounds__(1024) void lstm_rec(const u32* wregp, const u32* wldsp,
                                                 const float* G, const float* h0,
                                                 const float* c0, float* H) {
    __shared__ u32 Wl[32 * G4];            // 128KB, layout [16][1024][2]
    __shared__ float gates[G4];            // 4KB
    __shared__ __align__(16) u32 h2[128];  // 256 f16 of h (u32 p = h[2p],h[2p+1])
    int tid = threadIdx.x;
    int dir = blockIdx.x;
    {   // stage LDS weight slice, vectorized (linear copy preserves layout)
        const uint4* src = (const uint4*)(wldsp + (size_t)dir * 32 * G4);
        uint4* dst = (uint4*)Wl;
        for (int i = tid; i < 32 * G4 / 4; i += 1024) dst[i] = src[i];
    }
    const u32x16* wp = (const u32x16*)(wregp + ((size_t)dir * G4 + tid) * 96);
    u32x16 wA = wp[0], wB = wp[1], wC = wp[2], wD = wp[3], wE = wp[4], wF = wp[5];
    float cst = 0.0f;
    if (tid < HD) {
        cst = c0[dir * HD + tid];
        ((unsigned short*)h2)[tid] = __half_as_ushort(__float2half(h0[dir * HD + tid]));
    }
    __syncthreads();
    const float* Gd = G + (size_t)dir * TT * G4;
    float* Hd = H + (size_t)dir * TT * HD;
    for (int t = 0; t < TT; t++) {
        float g0 = Gd[(size_t)t * G4 + tid];   // issued early, used after dots
        float acc = 0.0f;
        DOT16(wA, 0)  DOT16(wB, 16) DOT16(wC, 32)
        DOT16(wD, 48) DOT16(wE, 64) DOT16(wF, 80)
#pragma unroll
        for (int k2 = 0; k2 < 16; k2 += 2) {   // K tail from LDS, b64 reads
            uint4 hh = *((const uint4*)&h2[96 + 2 * k2]);
            uint2 wa = *((const uint2*)&Wl[((size_t)k2 * G4 + tid) * 2]);
            acc = fdot2u(wa.x, hh.x, acc);
            acc = fdot2u(wa.y, hh.y, acc);
            uint2 wb = *((const uint2*)&Wl[(((size_t)k2 + 1) * G4 + tid) * 2]);
            acc = fdot2u(wb.x, hh.z, acc);
            acc = fdot2u(wb.y, hh.w, acc);
        }
        gates[tid] = acc + g0;
        __syncthreads();
        if (tid < 256) {
            float gi = gates[tid], gf = gates[tid + 256];
            float gg = gates[tid + 512], go = gates[tid + 768];
            cst = sigmf_(gf) * cst + sigmf_(gi) * tanhf_(gg);
            float h = sigmf_(go) * tanhf_(cst);
            Hd[(size_t)t * HD + tid] = h;
            ((unsigned short*)h2)[tid] = __half_as_ushort(__float2half(h));
        }
        __syncthreads();
    }
}

// K3: feats[t][n] = hf[t]·w_out[n][0:256] + hb_scan[T-1-t]·w_out[n][256:512] + b_out[n]
__global__ __launch_bounds__(256) void feats_kernel(const float* H, const float* w_out,
                                                    const float* b_out, float* feats) {
    int idx = blockIdx.x * blockDim.x + threadIdx.x;
    int t = idx >> 4, n = idx & 15;
    const float* hf = H + (size_t)t * HD;
    const float* hb = H + ((size_t)TT + (TT - 1 - t)) * HD;
    const float* w = w_out + (size_t)n * (2 * HD);
    float a = b_out[n];
    for (int k = 0; k < HD; k += 4) {
        float4 h4 = *((const float4*)&hf[k]);
        float4 w4 = *((const float4*)&w[k]);
        a += h4.x * w4.x + h4.y * w4.y + h4.z * w4.z + h4.w * w4.w;
    }
    for (int k = 0; k < HD; k += 4) {
        float4 h4 = *((const float4*)&hb[k]);
        float4 w4 = *((const float4*)&w[HD + k]);
        a += h4.x * w4.x + h4.y * w4.y + h4.z * w4.z + h4.w * w4.w;
    }
    feats[(size_t)t * NT + n] = a;
}

// K4: Viterbi + backtrack, single wave, shuffle-only recurrence.
// feats staged into LDS in 256-step chunks (kills the per-step global-load latency).
__global__ __launch_bounds__(64) void viterbi_kernel(const float* feats, const float* trans,
                                                     float* out) {
    __shared__ float fl[4096];              // 16KB: 256 steps x 16 tags
    __shared__ float fvs[NT];
    __shared__ unsigned char bps[TT][NT];   // 32KB
    int lane = threadIdx.x;
    int n = lane >> 2, pg = lane & 3;
    float4 tr4 = *((const float4*)&trans[n * NT + pg * 4]);
    float fv = (lane == START_TAG) ? 0.0f : NEGV;
    for (int c = 0; c < TT / 256; c++) {
        float4 st[16];
        const float4* src = (const float4*)(feats + c * 4096);
#pragma unroll
        for (int i = 0; i < 16; i++) st[i] = src[i * 64 + lane];
#pragma unroll
        for (int i = 0; i < 16; i++) *((float4*)&fl[(i * 64 + lane) * 4]) = st[i];
        __syncthreads();
        for (int tt = 0; tt < 256; tt++) {
            int t = c * 256 + tt;
            float f0 = __shfl(fv, pg * 4 + 0, 64);
            float f1 = __shfl(fv, pg * 4 + 1, 64);
            float f2 = __shfl(fv, pg * 4 + 2, 64);
            float f3 = __shfl(fv, pg * 4 + 3, 64);
            float ft = fl[tt * 16 + n];
            float v = f0 + tr4.x; int bi = pg * 4 + 0;
            float v1 = f1 + tr4.y; if (v1 > v) { v = v1; bi = pg * 4 + 1; }
            float v2 = f2 + tr4.z; if (v2 > v) { v = v2; bi = pg * 4 + 2; }
            float v3 = f3 + tr4.w; if (v3 > v) { v = v3; bi = pg * 4 + 3; }
#pragma unroll
            for (int m = 1; m <= 2; m <<= 1) {   // first-index tie-break
                float ov = __shfl_xor(v, m, 64);
                int ob = __shfl_xor(bi, m, 64);
                if (ov > v || (ov == v && ob < bi)) { v = ov; bi = ob; }
            }
            if (pg == 0) bps[t][n] = (unsigned char)bi;
            fv = __shfl(v + ft, (lane & 15) * 4, 64);
        }
        __syncthreads();
    }
    if (lane < NT) fvs[lane] = fv;
    __syncthreads();
    if (lane == 0) {
        float best = -3.0e38f; int bt = 0;
        for (int p = 0; p < NT; p++) {
            float tv = fvs[p] + trans[STOP_TAG * NT + p];
            if (tv > best) { best = tv; bt = p; }
        }
        out[0] = best;
        int tag = bt;
        out[TT] = (float)tag;                  // path[T-1]
        for (int t = TT - 2; t >= 0; t--) {
            tag = bps[t + 1][tag];
            out[1 + t] = (float)tag;
        }
    }
}

extern "C" void kernel_launch(void* const* d_in, const int* in_sizes, int n_in,
                              void* d_out, int out_size, void* d_ws, size_t ws_size,
                              hipStream_t stream) {
    const int* sent = (const int*)d_in[0];
    const float* embed = (const float*)d_in[1];
    const float* wih_f = (const float*)d_in[2];
    const float* whh_f = (const float*)d_in[3];
    const float* b_f = (const float*)d_in[4];
    const float* wih_b = (const float*)d_in[5];
    const float* whh_b = (const float*)d_in[6];
    const float* b_b = (const float*)d_in[7];
    const float* w_out = (const float*)d_in[8];
    const float* b_out = (const float*)d_in[9];
    const float* trans = (const float*)d_in[10];
    const float* h0 = (const float*)d_in[11];
    const float* c0 = (const float*)d_in[12];
    float* out = (float*)d_out;
    char* ws = (char*)d_ws;

    float* G = (float*)(ws);                               // 16MB
    float* H = (float*)(ws + (size_t)16 * 1024 * 1024);    // 4MB
    float* feats = (float*)(ws + (size_t)20 * 1024 * 1024);// 128KB
    u32* wregp = (u32*)(ws + (size_t)21 * 1024 * 1024);    // 768KB
    u32* wldsp = (u32*)(ws + (size_t)22 * 1024 * 1024);    // 256KB

    pack_whh<<<dim3(G4, 2), 128, 0, stream>>>(whh_f, whh_b, wregp, wldsp);
    input_gemm<<<dim3(TT / 32, G4 / 256, 2), 256, 0, stream>>>(sent, embed, wih_f, b_f,
                                                               wih_b, b_b, G);
    lstm_rec<<<dim3(2), 1024, 0, stream>>>(wregp, wldsp, G, h0, c0, H);
    feats_kernel<<<dim3(TT * NT / 256), 256, 0, stream>>>(H, w_out, b_out, feats);
    viterbi_kernel<<<dim3(1), 64, 0, stream>>>(feats, trans, out);
}